// Round 8
// baseline (213.074 us; speedup 1.0000x reference)
//
#include <hip/hip_runtime.h>

#define HH 256
#define WW 256
#define HWPX 65536
#define BB 8
#define KK 21
#define CC 32
#define NOUT (BB * KK)            // 168
#define AFF_BLOCKS 1024

typedef _Float16 half2v __attribute__((ext_vector_type(2)));
union F4H { float4 f4; half2v h[4]; };

// ---------------- kernel 1: T + |q|^2 + planar f16 pack, 1 px/thread ----------------
// fpk layout: plane j (8 channels), plane stride BB*HWPX float4s; within plane
// [global pixel idx] -> 16 B, lane-contiguous. 8192 waves for latency hiding.
__global__ __launch_bounds__(256) void prep(const float* __restrict__ cls,
                                            const float* __restrict__ feat,
                                            float4* __restrict__ fpk,
                                            float2* __restrict__ TN,
                                            float* __restrict__ accum /* numer|denom|counter */) {
    // zero the 336 accumulators + 1 counter (replaces hipMemsetAsync dispatch)
    if (blockIdx.x == 0) {
        for (int i = threadIdx.x; i < NOUT * 2 + 1; i += 256)
            ((unsigned*)accum)[i] = 0u;
    }

    const int tid = blockIdx.x * 256 + threadIdx.x;   // 0..524287 = b*HWPX+p
    const int b = tid >> 16;
    const int p = tid & (HWPX - 1);

    // T = sum_k S (21 independent scalar loads, coalesced 4 B/lane)
    const float* cbase = cls + (size_t)b * KK * HWPX + p;
    float s = 0.f;
#pragma unroll
    for (int k = 0; k < KK; ++k) s += cbase[(size_t)k * HWPX];

    const float* src = feat + (size_t)b * CC * HWPX + p;
    float nq = 0.f;
#pragma unroll 1   // runtime plane loop: 8 loads in flight per stage (hoist-window lesson)
    for (int j = 0; j < 4; ++j) {
        float ch[8];
#pragma unroll
        for (int c = 0; c < 8; ++c) ch[c] = src[(size_t)(j * 8 + c) * HWPX];
        F4H u;
#pragma unroll
        for (int k = 0; k < 4; ++k) {
            u.h[k] = __builtin_bit_cast(half2v, __builtin_amdgcn_cvt_pkrtz(ch[2 * k], ch[2 * k + 1]));
            nq = __builtin_amdgcn_fdot2(u.h[k], u.h[k], nq, false);
        }
        fpk[(size_t)j * (BB * HWPX) + tid] = u.f4;
    }
    TN[tid] = make_float2(s, nq);
}

// ---------------- kernel 2 (hot): affinity (dy-split) + reduction + inline finalize ----------------
// w(p,q) = exp(-off^2/16 - (|p|^2+|q|^2-2 p.q)); acc telescopes, w = exp2(2*log2e*acc).
// Each block does HALF the dy window for a 64x16 tile (linearity => partial V/deg
// can be reduced against cls independently). 1024 blocks = 4 waves/SIMD.
__global__ __launch_bounds__(256) void affinity6(const float4* __restrict__ fpk,
                                                 const float2* __restrict__ TN,
                                                 const float* __restrict__ cls,
                                                 float* __restrict__ numer,
                                                 float* __restrict__ denom,
                                                 unsigned* __restrict__ counter,
                                                 float* __restrict__ out) {
    __shared__ float smV[1024], smD[1024];
    __shared__ float pN[4][22], pD[4][22];
    __shared__ float sm[4];
    __shared__ unsigned sdone;

    // L%8 = batch (XCD round-robin => each XCD works one batch, L2-resident);
    // tile-halves are 8 apart in L => same XCD => 2nd cls pass mostly L2-hit.
    const int L    = blockIdx.x;          // 0..1023
    const int b    = L & 7;
    const int rest = L >> 3;
    const int half = rest & 1;            // dy-window half
    const int t    = rest >> 1;
    const int by   = t & 15;
    const int bx   = t >> 4;              // 0..3
    const int lane = threadIdx.x & 63;
    const int wid  = threadIdx.x >> 6;
    const int gx   = bx * 64 + lane;
    const int gy0  = by * 16 + wid * 4;   // owns rows gy0..gy0+3

    const size_t bofs = (size_t)b * HWPX;
    const float4* fb0 = fpk + bofs;
    const float4* fb1 = fpk + (size_t)1 * BB * HWPX + bofs;
    const float4* fb2 = fpk + (size_t)2 * BB * HWPX + bofs;
    const float4* fb3 = fpk + (size_t)3 * BB * HWPX + bofs;
    const float2* tnb = TN + bofs;

    F4H fp[4][4];
    float np_[4];
#pragma unroll
    for (int py = 0; py < 4; ++py) {
        const int pp = ((gy0 + py) << 8) | gx;
        fp[py][0].f4 = fb0[pp];
        fp[py][1].f4 = fb1[pp];
        fp[py][2].f4 = fb2[pp];
        fp[py][3].f4 = fb3[pp];
        np_[py] = tnb[pp].y;
    }

    float degacc[4] = {0.f, 0.f, 0.f, 0.f};
    float vacc[4]   = {0.f, 0.f, 0.f, 0.f};

    const int dy_lo = half * 6;           // [0,6) or [6,12)
    const int dy_hi = dy_lo + 6;

#pragma unroll 1   // runtime row loop: caps load-hoisting window (round-3 spill lesson)
    for (int dyi = dy_lo; dyi < dy_hi; ++dyi) {
        const int ny = gy0 + dyi - 4;               // neighbor row (same for all py)
        if ((unsigned)ny >= HH) continue;           // uniform
        const int rowq = ny << 8;

        int dy2[4];
        float base[4];
#pragma unroll
        for (int py = 0; py < 4; ++py) {
            const int d = dyi - 4 - py;             // uniform
            dy2[py] = d * d;
            base[py] = fmaf(-0.03125f, (float)dy2[py], -0.5f * np_[py]);
        }
        const int mind = min(min(dy2[0], dy2[1]), min(dy2[2], dy2[3]));

#pragma unroll 3
        for (int dxi = 0; dxi < 9; ++dxi) {
            const int dx = dxi - 4;                 // uniform
            const int dx2 = dx * dx;
            if (mind + dx2 >= 25) continue;         // uniform prune

            const int gx2 = gx + dx;
            const bool vx = (unsigned)gx2 < WW;     // per-lane x bound
            const int q = rowq | min(max(gx2, 0), WW - 1);

            F4H nb0, nb1, nb2, nb3;
            nb0.f4 = fb0[q];
            nb1.f4 = fb1[q];
            nb2.f4 = fb2[q];
            nb3.f4 = fb3[q];
            const float2 tq = tnb[q];
            const float cdx = (float)dx2 * -0.03125f;

#pragma unroll
            for (int py = 0; py < 4; ++py) {
                if (dy2[py] + dx2 < 25) {           // uniform circle test
                    float acc = fmaf(-0.5f, tq.y, base[py] + cdx);
#pragma unroll
                    for (int k = 0; k < 4; ++k) {
                        acc = __builtin_amdgcn_fdot2(fp[py][0].h[k], nb0.h[k], acc, false);
                        acc = __builtin_amdgcn_fdot2(fp[py][1].h[k], nb1.h[k], acc, false);
                        acc = __builtin_amdgcn_fdot2(fp[py][2].h[k], nb2.h[k], acc, false);
                        acc = __builtin_amdgcn_fdot2(fp[py][3].h[k], nb3.h[k], acc, false);
                    }
                    float w = __builtin_exp2f(acc * 2.8853900817779268f);  // exp(2*acc)
                    w = vx ? w : 0.f;
                    degacc[py] += w;
                    vacc[py] = fmaf(w, tq.x, vacc[py]);
                }
            }
        }
    }

    // ---- fused reduction epilogue (partial V/deg x cls, linear => additive) ----
#pragma unroll
    for (int py = 0; py < 4; ++py) {
        const int li = ((wid * 4 + py) << 6) | lane;   // local row-major 16x64
        smV[li] = vacc[py];
        smD[li] = degacc[py];
    }
    __syncthreads();

    const int li0 = threadIdx.x * 4;
    const int lr  = li0 >> 6;
    const int lc  = li0 & 63;
    const int gp  = ((by * 16 + lr) << 8) | (bx * 64 + lc);
    const float4 v4 = *(const float4*)&smV[li0];
    const float4 d4 = *(const float4*)&smD[li0];
    const float* clsb = cls + (size_t)b * KK * HWPX + gp;

    float accN[KK], accD[KK];
#pragma unroll 7
    for (int j = 0; j < KK; ++j) {
        float4 s4 = *(const float4*)(clsb + (size_t)j * HWPX);
        float n = s4.x * v4.x;   n = fmaf(s4.y, v4.y, n);
        n = fmaf(s4.z, v4.z, n); n = fmaf(s4.w, v4.w, n);
        float d = s4.x * d4.x;   d = fmaf(s4.y, d4.y, d);
        d = fmaf(s4.z, d4.z, d); d = fmaf(s4.w, d4.w, d);
        accN[j] = n; accD[j] = d;
    }

#pragma unroll
    for (int j = 0; j < KK; ++j) {
        float n = accN[j], d = accD[j];
#pragma unroll
        for (int off = 32; off > 0; off >>= 1) {
            n += __shfl_down(n, off);
            d += __shfl_down(d, off);
        }
        if (lane == 0) { pN[wid][j] = n; pD[wid][j] = d; }
    }
    __syncthreads();
    if (threadIdx.x < 2 * KK) {
        int h2 = threadIdx.x / KK;
        int j = threadIdx.x - h2 * KK;
        float acc = h2 ? (pD[0][j] + pD[1][j] + pD[2][j] + pD[3][j])
                       : (pN[0][j] + pN[1][j] + pN[2][j] + pN[3][j]);
        float* dst = h2 ? denom : numer;
        atomicAdd(&dst[b * KK + j], acc);
    }

    // ---- inline finalize: last block computes the scalar (replaces a dispatch) ----
    if (threadIdx.x == 0) {
        __threadfence();
        unsigned old = atomicAdd(counter, 1u);
        sdone = (old == (unsigned)(AFF_BLOCKS - 1)) ? 1u : 0u;
    }
    __syncthreads();
    if (sdone) {                                   // block-uniform condition
        const int i = threadIdx.x;
        float r = 0.f;
        if (i < NOUT) {
            float n = atomicAdd(&numer[i], 0.f);   // L1-bypassing device-scope reads
            float d = atomicAdd(&denom[i], 0.f);
            r = n / d;
        }
#pragma unroll
        for (int off = 32; off > 0; off >>= 1) r += __shfl_down(r, off);
        if ((i & 63) == 0) sm[i >> 6] = r;
        __syncthreads();
        if (i == 0) out[0] = sm[0] + sm[1] + sm[2] + sm[3];
    }
}

extern "C" void kernel_launch(void* const* d_in, const int* in_sizes, int n_in,
                              void* d_out, int out_size, void* d_ws, size_t ws_size,
                              hipStream_t stream) {
    const float* cls  = (const float*)d_in[0];  // [B,K,H,W]
    const float* feat = (const float*)d_in[1];  // [B,C,H,W]
    float* out = (float*)d_out;

    const size_t BHW = (size_t)BB * HWPX;
    // fpk (33.5 MB) | TN (4.2 MB) | numer[168] | denom[168] | counter
    float4*   fpk     = (float4*)d_ws;
    float2*   TN      = (float2*)((char*)d_ws + BHW * 64);
    float*    numer   = (float*)((char*)TN + BHW * 8);
    float*    denom   = numer + NOUT;
    unsigned* counter = (unsigned*)(denom + NOUT);

    prep<<<dim3(BHW / 256), dim3(256), 0, stream>>>(cls, feat, fpk, TN, numer);
    affinity6<<<dim3(AFF_BLOCKS), dim3(256), 0, stream>>>(fpk, TN, cls, numer, denom, counter, out);
}

// Round 9
// 211.806 us; speedup vs baseline: 1.0060x; 1.0060x over previous
//
#include <hip/hip_runtime.h>

#define HH 256
#define WW 256
#define HWPX 65536
#define BB 8
#define KK 21
#define CC 32
#define NOUT (BB * KK)            // 168
#define AFF_BLOCKS 512

typedef _Float16 half2v __attribute__((ext_vector_type(2)));
union F4H { float4 f4; half2v h[4]; };
union U1H { unsigned u; half2v h; };

__device__ __forceinline__ half2v pk(float a, float b) {
    return __builtin_bit_cast(half2v, __builtin_amdgcn_cvt_pkrtz(a, b));
}

// ---------------- kernel 1: contiguous-stream transpose prep ----------------
// Block owns 1024 consecutive px of one batch. All global reads are contiguous
// float4 streams within a channel plane (strided-stream theory: channel-major
// scalar streams run ~2.4 TB/s; contiguous runs ~6).  LDS transposes ch->px.
__global__ __launch_bounds__(256) void prep(const float* __restrict__ cls,
                                            const float* __restrict__ feat,
                                            uint4* __restrict__ fpk,
                                            float2* __restrict__ TN,
                                            float* __restrict__ accum) {
    __shared__ unsigned ldsW[4][1024];   // [channel-pair][local px]
    __shared__ float    ldsT[1024];

    if (blockIdx.x == 0) {               // zero numer|denom|counter (replaces memset)
        for (int i = threadIdx.x; i < NOUT * 2 + 1; i += 256)
            ((unsigned*)accum)[i] = 0u;
    }

    const int b    = blockIdx.x >> 6;    // 512 blocks = 8 b x 64 tiles
    const int tile = blockIdx.x & 63;
    const int px0  = tile << 10;
    const int t    = threadIdx.x;
    const size_t gbase = (size_t)b * HWPX + px0;

    // phase 1: T = sum_k S  (contiguous float4 per k-plane)
    const float* cb = cls + (size_t)b * KK * HWPX + px0 + 4 * t;
    float4 s = make_float4(0.f, 0.f, 0.f, 0.f);
#pragma unroll
    for (int k = 0; k < KK; ++k) {
        float4 c = *(const float4*)(cb + (size_t)k * HWPX);
        s.x += c.x; s.y += c.y; s.z += c.z; s.w += c.w;
    }
    *(float4*)&ldsT[4 * t] = s;          // ds_write_b128, conflict-free

    // phase 2: feature planes
    const float* fb = feat + (size_t)b * CC * HWPX + px0 + 4 * t;
    float nqacc[4] = {0.f, 0.f, 0.f, 0.f};
#pragma unroll 1
    for (int j = 0; j < 4; ++j) {
#pragma unroll
        for (int cp = 0; cp < 4; ++cp) { // 8 contiguous float4 streams in flight
            float4 a = *(const float4*)(fb + (size_t)(8 * j + 2 * cp) * HWPX);
            float4 c = *(const float4*)(fb + (size_t)(8 * j + 2 * cp + 1) * HWPX);
            uint4 u;
            u.x = __builtin_bit_cast(unsigned, pk(a.x, c.x));
            u.y = __builtin_bit_cast(unsigned, pk(a.y, c.y));
            u.z = __builtin_bit_cast(unsigned, pk(a.z, c.z));
            u.w = __builtin_bit_cast(unsigned, pk(a.w, c.w));
            *(uint4*)&ldsW[cp][4 * t] = u;   // px 4t..4t+3, word cp; conflict-free
        }
        __syncthreads();
#pragma unroll
        for (int r = 0; r < 4; ++r) {
            const int lp = (r << 8) + t;     // fixed px ownership across j
            U1H w0, w1, w2, w3;
            w0.u = ldsW[0][lp]; w1.u = ldsW[1][lp];   // lane-consecutive words,
            w2.u = ldsW[2][lp]; w3.u = ldsW[3][lp];   // conflict-free
            float nq = nqacc[r];
            nq = __builtin_amdgcn_fdot2(w0.h, w0.h, nq, false);
            nq = __builtin_amdgcn_fdot2(w1.h, w1.h, nq, false);
            nq = __builtin_amdgcn_fdot2(w2.h, w2.h, nq, false);
            nq = __builtin_amdgcn_fdot2(w3.h, w3.h, nq, false);
            nqacc[r] = nq;
            uint4 rec = make_uint4(w0.u, w1.u, w2.u, w3.u);
            fpk[(size_t)j * (BB * HWPX) + gbase + lp] = rec;  // coalesced b128
        }
        __syncthreads();
    }
    // final: TN (coalesced b64)
#pragma unroll
    for (int r = 0; r < 4; ++r) {
        const int lp = (r << 8) + t;
        TN[gbase + lp] = make_float2(ldsT[lp], nqacc[r]);
    }
}

// ---------------- kernel 2 (hot): r7 affinity5 + counter-based inline finalize ----------------
__global__ __launch_bounds__(256) void affinity5(const float4* __restrict__ fpk,
                                                 const float2* __restrict__ TN,
                                                 const float* __restrict__ cls,
                                                 float* __restrict__ numer,
                                                 float* __restrict__ denom,
                                                 unsigned* __restrict__ counter,
                                                 float* __restrict__ out) {
    __shared__ float smV[1024], smD[1024];
    __shared__ float pN[4][22], pD[4][22];
    __shared__ float sm[4];
    __shared__ unsigned sdone;

    // XCD swizzle: L%8 = batch -> each XCD's share is one batch (~4.7 MB, L2-resident)
    const int L  = blockIdx.x;            // 0..511
    const int b  = L & 7;
    const int t  = L >> 3;
    const int by = t & 15;
    const int bx = t >> 4;                // 0..3
    const int lane = threadIdx.x & 63;
    const int wid  = threadIdx.x >> 6;
    const int gx  = bx * 64 + lane;
    const int gy0 = by * 16 + wid * 4;    // owns rows gy0..gy0+3

    const size_t bofs = (size_t)b * HWPX;
    const float4* fb0 = fpk + bofs;
    const float4* fb1 = fpk + (size_t)1 * BB * HWPX + bofs;
    const float4* fb2 = fpk + (size_t)2 * BB * HWPX + bofs;
    const float4* fb3 = fpk + (size_t)3 * BB * HWPX + bofs;
    const float2* tnb = TN + bofs;

    F4H fp[4][4];
    float np_[4];
#pragma unroll
    for (int py = 0; py < 4; ++py) {
        const int pp = ((gy0 + py) << 8) | gx;
        fp[py][0].f4 = fb0[pp];
        fp[py][1].f4 = fb1[pp];
        fp[py][2].f4 = fb2[pp];
        fp[py][3].f4 = fb3[pp];
        np_[py] = tnb[pp].y;
    }

    float degacc[4] = {0.f, 0.f, 0.f, 0.f};
    float vacc[4]   = {0.f, 0.f, 0.f, 0.f};

#pragma unroll 1   // runtime row loop: caps load-hoisting window (round-3 spill lesson)
    for (int dyi = 0; dyi < 12; ++dyi) {
        const int ny = gy0 + dyi - 4;
        if ((unsigned)ny >= HH) continue;           // uniform
        const int rowq = ny << 8;

        int dy2[4];
        float base[4];
#pragma unroll
        for (int py = 0; py < 4; ++py) {
            const int d = dyi - 4 - py;
            dy2[py] = d * d;
            base[py] = fmaf(-0.03125f, (float)dy2[py], -0.5f * np_[py]);
        }
        const int mind = min(min(dy2[0], dy2[1]), min(dy2[2], dy2[3]));

#pragma unroll 3
        for (int dxi = 0; dxi < 9; ++dxi) {
            const int dx = dxi - 4;
            const int dx2 = dx * dx;
            if (mind + dx2 >= 25) continue;         // uniform prune

            const int gx2 = gx + dx;
            const bool vx = (unsigned)gx2 < WW;
            const int q = rowq | min(max(gx2, 0), WW - 1);

            F4H nb0, nb1, nb2, nb3;
            nb0.f4 = fb0[q];
            nb1.f4 = fb1[q];
            nb2.f4 = fb2[q];
            nb3.f4 = fb3[q];
            const float2 tq = tnb[q];
            const float cdx = (float)dx2 * -0.03125f;

#pragma unroll
            for (int py = 0; py < 4; ++py) {
                if (dy2[py] + dx2 < 25) {
                    float acc = fmaf(-0.5f, tq.y, base[py] + cdx);
#pragma unroll
                    for (int k = 0; k < 4; ++k) {
                        acc = __builtin_amdgcn_fdot2(fp[py][0].h[k], nb0.h[k], acc, false);
                        acc = __builtin_amdgcn_fdot2(fp[py][1].h[k], nb1.h[k], acc, false);
                        acc = __builtin_amdgcn_fdot2(fp[py][2].h[k], nb2.h[k], acc, false);
                        acc = __builtin_amdgcn_fdot2(fp[py][3].h[k], nb3.h[k], acc, false);
                    }
                    float w = __builtin_exp2f(acc * 2.8853900817779268f);  // exp(2*acc)
                    w = vx ? w : 0.f;
                    degacc[py] += w;
                    vacc[py] = fmaf(w, tq.x, vacc[py]);
                }
            }
        }
    }

    // ---- fused reduction epilogue ----
#pragma unroll
    for (int py = 0; py < 4; ++py) {
        const int li = ((wid * 4 + py) << 6) | lane;
        smV[li] = vacc[py];
        smD[li] = degacc[py];
    }
    __syncthreads();

    const int li0 = threadIdx.x * 4;
    const int lr  = li0 >> 6;
    const int lc  = li0 & 63;
    const int gp  = ((by * 16 + lr) << 8) | (bx * 64 + lc);
    const float4 v4 = *(const float4*)&smV[li0];
    const float4 d4 = *(const float4*)&smD[li0];
    const float* clsb = cls + (size_t)b * KK * HWPX + gp;

    float accN[KK], accD[KK];
#pragma unroll 7
    for (int j = 0; j < KK; ++j) {
        float4 s4 = *(const float4*)(clsb + (size_t)j * HWPX);
        float n = s4.x * v4.x;   n = fmaf(s4.y, v4.y, n);
        n = fmaf(s4.z, v4.z, n); n = fmaf(s4.w, v4.w, n);
        float d = s4.x * d4.x;   d = fmaf(s4.y, d4.y, d);
        d = fmaf(s4.z, d4.z, d); d = fmaf(s4.w, d4.w, d);
        accN[j] = n; accD[j] = d;
    }

#pragma unroll
    for (int j = 0; j < KK; ++j) {
        float n = accN[j], d = accD[j];
#pragma unroll
        for (int off = 32; off > 0; off >>= 1) {
            n += __shfl_down(n, off);
            d += __shfl_down(d, off);
        }
        if (lane == 0) { pN[wid][j] = n; pD[wid][j] = d; }
    }
    __syncthreads();
    if (threadIdx.x < 2 * KK) {
        int h2 = threadIdx.x / KK;
        int j = threadIdx.x - h2 * KK;
        float acc = h2 ? (pD[0][j] + pD[1][j] + pD[2][j] + pD[3][j])
                       : (pN[0][j] + pN[1][j] + pN[2][j] + pN[3][j]);
        float* dst = h2 ? denom : numer;
        atomicAdd(&dst[b * KK + j], acc);
    }

    // ---- inline finalize: last block computes the scalar ----
    if (threadIdx.x == 0) {
        __threadfence();
        unsigned old = atomicAdd(counter, 1u);
        sdone = (old == (unsigned)(AFF_BLOCKS - 1)) ? 1u : 0u;
    }
    __syncthreads();
    if (sdone) {
        const int i = threadIdx.x;
        float r = 0.f;
        if (i < NOUT) {
            float n = atomicAdd(&numer[i], 0.f);
            float d = atomicAdd(&denom[i], 0.f);
            r = n / d;
        }
#pragma unroll
        for (int off = 32; off > 0; off >>= 1) r += __shfl_down(r, off);
        if ((i & 63) == 0) sm[i >> 6] = r;
        __syncthreads();
        if (i == 0) out[0] = sm[0] + sm[1] + sm[2] + sm[3];
    }
}

extern "C" void kernel_launch(void* const* d_in, const int* in_sizes, int n_in,
                              void* d_out, int out_size, void* d_ws, size_t ws_size,
                              hipStream_t stream) {
    const float* cls  = (const float*)d_in[0];  // [B,K,H,W]
    const float* feat = (const float*)d_in[1];  // [B,C,H,W]
    float* out = (float*)d_out;

    const size_t BHW = (size_t)BB * HWPX;
    // fpk (33.5 MB) | TN (4.2 MB) | numer[168] | denom[168] | counter
    uint4*    fpk     = (uint4*)d_ws;
    float2*   TN      = (float2*)((char*)d_ws + BHW * 64);
    float*    numer   = (float*)((char*)TN + BHW * 8);
    float*    denom   = numer + NOUT;
    unsigned* counter = (unsigned*)(denom + NOUT);

    prep<<<dim3(512), dim3(256), 0, stream>>>(cls, feat, fpk, TN, numer);
    affinity5<<<dim3(AFF_BLOCKS), dim3(256), 0, stream>>>((const float4*)fpk, TN, cls,
                                                          numer, denom, counter, out);
}